// Round 1
// baseline (3997.078 us; speedup 1.0000x reference)
//
#include <hip/hip_runtime.h>
#include <hip/hip_bf16.h>

#define N_NODES 50000
#define N_EDGES 600000
#define CH 128
#define N_LAYERS 15

__device__ __forceinline__ float eluf(float v) {
    return v > 0.f ? v : (__expf(v) - 1.f);
}

// ---------------- conv1: [N,3] @ [3,128] + b ----------------
__global__ __launch_bounds__(256) void conv1_kernel(
    const float* __restrict__ in, const float* __restrict__ W1,
    const float* __restrict__ b1, float* __restrict__ x, int n)
{
    int idx = blockIdx.x * blockDim.x + threadIdx.x;
    if (idx >= n * CH) return;
    int node = idx >> 7;
    int c = idx & 127;
    float o = b1[c]
            + in[(size_t)node * 3 + 0] * W1[0 * CH + c]
            + in[(size_t)node * 3 + 1] * W1[1 * CH + c]
            + in[(size_t)node * 3 + 2] * W1[2 * CH + c];
    x[idx] = o;
}

// ---------------- CSR build ----------------
__global__ __launch_bounds__(256) void zero_int_kernel(int* __restrict__ p, int n) {
    int i = blockIdx.x * blockDim.x + threadIdx.x;
    if (i < n) p[i] = 0;
}

__global__ __launch_bounds__(256) void count_kernel(
    const int* __restrict__ row, int* __restrict__ cnt, int e)
{
    int i = blockIdx.x * blockDim.x + threadIdx.x;
    if (i < e) atomicAdd(&cnt[row[i]], 1);
}

__global__ __launch_bounds__(1024) void scan_kernel(
    const int* __restrict__ cnt, int* __restrict__ row_ptr, int n)
{
    __shared__ int sdata[1024];
    __shared__ int carry_s;
    int tid = threadIdx.x;
    if (tid == 0) { carry_s = 0; row_ptr[0] = 0; }
    __syncthreads();
    for (int base = 0; base < n; base += 1024) {
        int v = (base + tid < n) ? cnt[base + tid] : 0;
        sdata[tid] = v;
        __syncthreads();
        for (int off = 1; off < 1024; off <<= 1) {
            int t = 0;
            if (tid >= off) t = sdata[tid - off];
            __syncthreads();
            sdata[tid] += t;
            __syncthreads();
        }
        int c = carry_s;
        if (base + tid < n) row_ptr[base + tid + 1] = c + sdata[tid];
        __syncthreads();
        if (tid == 0) carry_s = c + sdata[1023];
        __syncthreads();
    }
}

__global__ __launch_bounds__(256) void fill_kernel(
    const int* __restrict__ row, const int* __restrict__ col,
    const float* __restrict__ val, int* __restrict__ cursor,
    const int* __restrict__ row_ptr, int* __restrict__ col_s,
    float* __restrict__ val_s, int e)
{
    int i = blockIdx.x * blockDim.x + threadIdx.x;
    if (i >= e) return;
    int r = row[i];
    int pos = atomicAdd(&cursor[r], 1);
    int dst = row_ptr[r] + pos;
    col_s[dst] = col[i];
    val_s[dst] = val[i];
}

// ---------------- Laplacian: prop[n,:] = sum_e val*elu(x[col,:]) ----------------
__global__ __launch_bounds__(256) void lap_kernel(
    const int* __restrict__ rp, const int* __restrict__ cols,
    const float* __restrict__ vals, const float* __restrict__ x,
    float* __restrict__ prop, int n)
{
    int wave = (blockIdx.x * blockDim.x + threadIdx.x) >> 6;
    int lane = threadIdx.x & 63;
    if (wave >= n) return;
    int s = rp[wave], e = rp[wave + 1];
    int c = lane * 2;
    float2 acc = {0.f, 0.f};
    for (int t = s; t < e; ++t) {
        int col = cols[t];
        float v = vals[t];
        float2 h = *(const float2*)(x + (size_t)col * CH + c);
        h.x = eluf(h.x); h.y = eluf(h.y);
        acc.x += v * h.x; acc.y += v * h.y;
    }
    *(float2*)(prop + (size_t)wave * CH + c) = acc;
}

// ---------------- avg layer: partial sums of mask*elu(x) ----------------
__global__ __launch_bounds__(256) void avg_reduce_kernel(
    const float* __restrict__ x, const float* __restrict__ mask,
    float* __restrict__ part, int n)
{
    int c = threadIdx.x & 127;
    int sub = threadIdx.x >> 7;                // 0/1
    int rowid = blockIdx.x * 2 + sub;          // 0..511
    float acc = 0.f;
    for (int node = rowid; node < n; node += gridDim.x * 2) {
        acc += mask[node] * eluf(x[(size_t)node * CH + c]);
    }
    part[(size_t)rowid * CH + c] = acc;
}

// bias2[c] = b[c] + sum_k (avg_h[k]) * Wb[k][c]
__global__ __launch_bounds__(128) void avg_bias_kernel(
    const float* __restrict__ part, const float* __restrict__ mask,
    const float* __restrict__ Wb, const float* __restrict__ b,
    float* __restrict__ bias2, int n)
{
    __shared__ float avg_s[128];
    __shared__ float dsum[128];
    int c = threadIdx.x;
    float s = 0.f;
    for (int r = 0; r < 512; ++r) s += part[(size_t)r * CH + c];
    float dn = 0.f;
    for (int i = c; i < n; i += 128) dn += mask[i];
    dsum[c] = dn;
    __syncthreads();
    for (int off = 64; off > 0; off >>= 1) {
        if (c < off) dsum[c] += dsum[c + off];
        __syncthreads();
    }
    float denom = dsum[0];
    avg_s[c] = s / denom;
    __syncthreads();
    float o = b[c];
    for (int k = 0; k < 128; ++k) o += avg_s[k] * Wb[(size_t)k * CH + c];
    bias2[c] = o;
}

// ---------------- GEMM: out = elu(A0) @ W[0:128] (+ A1 @ W[128:256]) + bias (+ res)
// tile: 128 nodes x 128 cols, 256 threads, 8x8 micro-tile, BK=32
__global__ __launch_bounds__(256) void gemm_kernel(
    const float* __restrict__ A0, const float* __restrict__ A1,
    const float* __restrict__ W, const float* __restrict__ bias,
    const float* __restrict__ res, float* __restrict__ out, int n)
{
    __shared__ float As[128][33];
    __shared__ float Ws[32][128];
    const int tid = threadIdx.x;
    const int m_base = blockIdx.x * 128;
    const int nch = (A1 != nullptr) ? 8 : 4;
    float acc[8][8];
#pragma unroll
    for (int i = 0; i < 8; i++)
#pragma unroll
        for (int j = 0; j < 8; j++) acc[i][j] = 0.f;
    const int m0 = (tid >> 4) << 3;
    const int c0 = (tid & 15) << 3;

    for (int ch = 0; ch < nch; ++ch) {
        const int k0 = ch * 32;
        const float* src = (k0 < 128) ? A0 : A1;
        const int kcol = (k0 < 128) ? k0 : (k0 - 128);
        const bool do_elu = (k0 < 128);
        // stage A tile: 128 rows x 32 cols
#pragma unroll
        for (int it = 0; it < 4; ++it) {
            int f = tid + it * 256;         // float4 id, 1024 total
            int r = f >> 3;                 // 8 float4 per row
            int cc = (f & 7) << 2;
            int node = m_base + r;
            float4 v = {0.f, 0.f, 0.f, 0.f};
            if (node < n) v = *(const float4*)(src + (size_t)node * CH + kcol + cc);
            if (do_elu) { v.x = eluf(v.x); v.y = eluf(v.y); v.z = eluf(v.z); v.w = eluf(v.w); }
            As[r][cc]     = v.x;
            As[r][cc + 1] = v.y;
            As[r][cc + 2] = v.z;
            As[r][cc + 3] = v.w;
        }
        // stage W tile: 32 rows x 128 cols
#pragma unroll
        for (int it = 0; it < 4; ++it) {
            int f = tid + it * 256;
            int kr = f >> 5;                // 32 float4 per row
            int wc = (f & 31) << 2;
            float4 v = *(const float4*)(W + (size_t)(k0 + kr) * CH + wc);
            *(float4*)&Ws[kr][wc] = v;
        }
        __syncthreads();
#pragma unroll
        for (int kk = 0; kk < 32; ++kk) {
            float a[8];
#pragma unroll
            for (int i = 0; i < 8; i++) a[i] = As[m0 + i][kk];
            float4 w0 = *(const float4*)&Ws[kk][c0];
            float4 w1 = *(const float4*)&Ws[kk][c0 + 4];
#pragma unroll
            for (int i = 0; i < 8; i++) {
                acc[i][0] += a[i] * w0.x; acc[i][1] += a[i] * w0.y;
                acc[i][2] += a[i] * w0.z; acc[i][3] += a[i] * w0.w;
                acc[i][4] += a[i] * w1.x; acc[i][5] += a[i] * w1.y;
                acc[i][6] += a[i] * w1.z; acc[i][7] += a[i] * w1.w;
            }
        }
        __syncthreads();
    }
    float4 bv0 = *(const float4*)(bias + c0);
    float4 bv1 = *(const float4*)(bias + c0 + 4);
#pragma unroll
    for (int i = 0; i < 8; i++) {
        int node = m_base + m0 + i;
        if (node >= n) continue;
        float4 o0 = {acc[i][0] + bv0.x, acc[i][1] + bv0.y, acc[i][2] + bv0.z, acc[i][3] + bv0.w};
        float4 o1 = {acc[i][4] + bv1.x, acc[i][5] + bv1.y, acc[i][6] + bv1.z, acc[i][7] + bv1.w};
        if (res) {
            float4 r0 = *(const float4*)(res + (size_t)node * CH + c0);
            float4 r1 = *(const float4*)(res + (size_t)node * CH + c0 + 4);
            o0.x += r0.x; o0.y += r0.y; o0.z += r0.z; o0.w += r0.w;
            o1.x += r1.x; o1.y += r1.y; o1.z += r1.z; o1.w += r1.w;
        }
        *(float4*)(out + (size_t)node * CH + c0)     = o0;
        *(float4*)(out + (size_t)node * CH + c0 + 4) = o1;
    }
}

// ---------------- final head: out[n] = elu(x[n]) @ W2 + b2 + inputs[n,0] ----------------
__global__ __launch_bounds__(256) void final_kernel(
    const float* __restrict__ x, const float* __restrict__ W2,
    const float* __restrict__ b2, const float* __restrict__ in,
    float* __restrict__ out, int n)
{
    int wave = (blockIdx.x * blockDim.x + threadIdx.x) >> 6;
    int lane = threadIdx.x & 63;
    if (wave >= n) return;
    float v = eluf(x[(size_t)wave * CH + lane]) * W2[lane]
            + eluf(x[(size_t)wave * CH + 64 + lane]) * W2[64 + lane];
#pragma unroll
    for (int off = 32; off > 0; off >>= 1) v += __shfl_down(v, off, 64);
    if (lane == 0) out[wave] = v + b2[0] + in[(size_t)wave * 3];
}

extern "C" void kernel_launch(void* const* d_in, const int* in_sizes, int n_in,
                              void* d_out, int out_size, void* d_ws, size_t ws_size,
                              hipStream_t stream)
{
    const int*   L_row   = (const int*)d_in[0];
    const int*   L_col   = (const int*)d_in[1];
    const float* L_val   = (const float*)d_in[2];
    const float* mask    = (const float*)d_in[3];
    const float* inputs  = (const float*)d_in[4];
    const float* conv1_W = (const float*)d_in[5];
    const float* conv1_b = (const float*)d_in[6];
    const float* blocks_W = (const float*)d_in[7];
    const float* blocks_b = (const float*)d_in[8];
    const float* conv2_W = (const float*)d_in[9];
    const float* conv2_b = (const float*)d_in[10];
    float* out = (float*)d_out;

    const int N = N_NODES, E = N_EDGES;
    const size_t NF = (size_t)N * CH;
    const int NPAD = 50048;  // N rounded up, keeps 16B alignment

    float* ws = (float*)d_ws;
    float* bufA = ws;
    float* bufB = bufA + NF;
    float* bufC = bufB + NF;
    float* prop = bufC + NF;
    int* cnt     = (int*)(prop + NF);
    int* cursor  = cnt + NPAD;
    int* row_ptr = cursor + NPAD;
    int* col_s   = row_ptr + NPAD;
    float* val_s = (float*)(col_s + E);
    float* part  = val_s + E;
    float* bias2 = part + (size_t)512 * CH;

    // CSR build (same every call; inputs are restored before each timed run)
    zero_int_kernel<<<(2 * NPAD + 255) / 256, 256, 0, stream>>>(cnt, 2 * NPAD);
    count_kernel<<<(E + 255) / 256, 256, 0, stream>>>(L_row, cnt, E);
    scan_kernel<<<1, 1024, 0, stream>>>(cnt, row_ptr, N);
    fill_kernel<<<(E + 255) / 256, 256, 0, stream>>>(L_row, L_col, L_val, cursor,
                                                     row_ptr, col_s, val_s, E);

    conv1_kernel<<<(N * CH + 255) / 256, 256, 0, stream>>>(inputs, conv1_W, conv1_b, bufA, N);

    float* bufs[3] = {bufA, bufB, bufC};
    int cur = 0;
    const int gemm_grid = (N + 127) / 128;      // 391
    const int wave_grid = (N + 3) / 4;          // 12500 blocks of 4 waves

    for (int i = 0; i < N_LAYERS; ++i) {
        float* t1 = bufs[(cur + 1) % 3];
        float* t2 = bufs[(cur + 2) % 3];
        const float* xin = bufs[cur];
        for (int j = 0; j < 2; ++j) {
            const float* W = blocks_W + (size_t)(i * 2 + j) * 256 * CH;
            const float* b = blocks_b + (size_t)(i * 2 + j) * CH;
            const float* src = (j == 0) ? xin : t1;
            float* dst = (j == 0) ? t1 : t2;
            const float* resp = (j == 1) ? xin : nullptr;
            if (i % 2 == 0) {
                lap_kernel<<<wave_grid, 256, 0, stream>>>(row_ptr, col_s, val_s, src, prop, N);
                gemm_kernel<<<gemm_grid, 256, 0, stream>>>(src, prop, W, b, resp, dst, N);
            } else {
                avg_reduce_kernel<<<256, 256, 0, stream>>>(src, mask, part, N);
                avg_bias_kernel<<<1, 128, 0, stream>>>(part, mask, W + 128 * CH, b, bias2, N);
                gemm_kernel<<<gemm_grid, 256, 0, stream>>>(src, nullptr, W, bias2, resp, dst, N);
            }
        }
        cur = (cur + 2) % 3;
    }
    final_kernel<<<wave_grid, 256, 0, stream>>>(bufs[cur], conv2_W, conv2_b, inputs, out, N);
}

// Round 2
// 3352.190 us; speedup vs baseline: 1.1924x; 1.1924x over previous
//
#include <hip/hip_runtime.h>
#include <hip/hip_bf16.h>

#define N_NODES 50000
#define N_EDGES 600000
#define CH 128
#define N_LAYERS 15

__device__ __forceinline__ float eluf(float v) {
    return v > 0.f ? v : (__expf(v) - 1.f);
}

// ---------------- conv1: [N,3] @ [3,128] + b ----------------
__global__ __launch_bounds__(256) void conv1_kernel(
    const float* __restrict__ in, const float* __restrict__ W1,
    const float* __restrict__ b1, float* __restrict__ x, int n)
{
    int idx = blockIdx.x * blockDim.x + threadIdx.x;
    if (idx >= n * CH) return;
    int node = idx >> 7;
    int c = idx & 127;
    float o = b1[c]
            + in[(size_t)node * 3 + 0] * W1[0 * CH + c]
            + in[(size_t)node * 3 + 1] * W1[1 * CH + c]
            + in[(size_t)node * 3 + 2] * W1[2 * CH + c];
    x[idx] = o;
}

// ---------------- zero helpers ----------------
__global__ __launch_bounds__(256) void zero_int_kernel(int* __restrict__ p, int n) {
    int i = blockIdx.x * blockDim.x + threadIdx.x;
    if (i < n) p[i] = 0;
}

__global__ __launch_bounds__(256) void zero_float_kernel(float* __restrict__ p, int n) {
    int i = blockIdx.x * blockDim.x + threadIdx.x;
    if (i < n) p[i] = 0.f;
}

// ---------------- CSR build ----------------
__global__ __launch_bounds__(256) void count_kernel(
    const int* __restrict__ row, int* __restrict__ cnt, int e)
{
    int i = blockIdx.x * blockDim.x + threadIdx.x;
    if (i < e) atomicAdd(&cnt[row[i]], 1);
}

__global__ __launch_bounds__(1024) void scan_kernel(
    const int* __restrict__ cnt, int* __restrict__ row_ptr, int n)
{
    __shared__ int sdata[1024];
    __shared__ int carry_s;
    int tid = threadIdx.x;
    if (tid == 0) { carry_s = 0; row_ptr[0] = 0; }
    __syncthreads();
    for (int base = 0; base < n; base += 1024) {
        int v = (base + tid < n) ? cnt[base + tid] : 0;
        sdata[tid] = v;
        __syncthreads();
        for (int off = 1; off < 1024; off <<= 1) {
            int t = 0;
            if (tid >= off) t = sdata[tid - off];
            __syncthreads();
            sdata[tid] += t;
            __syncthreads();
        }
        int c = carry_s;
        if (base + tid < n) row_ptr[base + tid + 1] = c + sdata[tid];
        __syncthreads();
        if (tid == 0) carry_s = c + sdata[1023];
        __syncthreads();
    }
}

__global__ __launch_bounds__(256) void fill_kernel(
    const int* __restrict__ row, const int* __restrict__ col,
    const float* __restrict__ val, int* __restrict__ cursor,
    const int* __restrict__ row_ptr, int* __restrict__ col_s,
    float* __restrict__ val_s, int e)
{
    int i = blockIdx.x * blockDim.x + threadIdx.x;
    if (i >= e) return;
    int r = row[i];
    int pos = atomicAdd(&cursor[r], 1);
    int dst = row_ptr[r] + pos;
    col_s[dst] = col[i];
    val_s[dst] = val[i];
}

// ---------------- mask denominator (once per call) ----------------
__global__ __launch_bounds__(256) void mask_sum_kernel(
    const float* __restrict__ mask, float* __restrict__ denom, int n)
{
    __shared__ float sd[256];
    int tid = threadIdx.x;
    float s = 0.f;
    for (int i = blockIdx.x * 256 + tid; i < n; i += gridDim.x * 256) s += mask[i];
    sd[tid] = s;
    __syncthreads();
    for (int off = 128; off > 0; off >>= 1) {
        if (tid < off) sd[tid] += sd[tid + off];
        __syncthreads();
    }
    if (tid == 0) atomicAdd(denom, sd[0]);
}

// ---------------- Laplacian: prop[n,:] = sum_e val*elu(x[col,:]) ----------------
__global__ __launch_bounds__(256) void lap_kernel(
    const int* __restrict__ rp, const int* __restrict__ cols,
    const float* __restrict__ vals, const float* __restrict__ x,
    float* __restrict__ prop, int n)
{
    int wave = (blockIdx.x * blockDim.x + threadIdx.x) >> 6;
    int lane = threadIdx.x & 63;
    if (wave >= n) return;
    int s = rp[wave], e = rp[wave + 1];
    int c = lane * 2;
    float2 acc = {0.f, 0.f};
    for (int t = s; t < e; ++t) {
        int col = cols[t];
        float v = vals[t];
        float2 h = *(const float2*)(x + (size_t)col * CH + c);
        h.x = eluf(h.x); h.y = eluf(h.y);
        acc.x += v * h.x; acc.y += v * h.y;
    }
    *(float2*)(prop + (size_t)wave * CH + c) = acc;
}

// ---------------- avg layer: atomic accumulate sum of mask*elu(x) into acc[128] ----------------
__global__ __launch_bounds__(256) void avg_reduce_kernel(
    const float* __restrict__ x, const float* __restrict__ mask,
    float* __restrict__ acc, int n)
{
    __shared__ float sd[256];
    int c = threadIdx.x & 127;
    int sub = threadIdx.x >> 7;                // 0/1
    int rowid = blockIdx.x * 2 + sub;
    float a = 0.f;
    for (int node = rowid; node < n; node += gridDim.x * 2) {
        a += mask[node] * eluf(x[(size_t)node * CH + c]);
    }
    sd[threadIdx.x] = a;
    __syncthreads();
    if (threadIdx.x < 128)
        atomicAdd(&acc[threadIdx.x], sd[threadIdx.x] + sd[threadIdx.x + 128]);
}

// bias2[c] = b[c] + sum_k (acc[k]/denom) * Wb[k][c]   (split-k over 2 halves)
__global__ __launch_bounds__(256) void avg_bias_kernel(
    const float* __restrict__ acc, const float* __restrict__ denom,
    const float* __restrict__ Wb, const float* __restrict__ b,
    float* __restrict__ bias2)
{
    __shared__ float avg_s[128];
    __shared__ float partial[256];
    int tid = threadIdx.x;
    if (tid < 128) avg_s[tid] = acc[tid] / denom[0];
    __syncthreads();
    int c = tid & 127;
    int h = tid >> 7;
    float o = 0.f;
#pragma unroll 8
    for (int k = h * 64; k < h * 64 + 64; ++k) o += avg_s[k] * Wb[(size_t)k * CH + c];
    partial[tid] = o;
    __syncthreads();
    if (tid < 128) bias2[tid] = b[tid] + partial[tid] + partial[tid + 128];
}

// ---------------- GEMM: out = elu(A0) @ W[0:128] (+ A1 @ W[128:256]) + bias (+ res)
// tile: 128 nodes x 128 cols, 256 threads, 8x8 micro-tile, BK=32
__global__ __launch_bounds__(256) void gemm_kernel(
    const float* __restrict__ A0, const float* __restrict__ A1,
    const float* __restrict__ W, const float* __restrict__ bias,
    const float* __restrict__ res, float* __restrict__ out, int n)
{
    __shared__ float As[128][33];
    __shared__ float Ws[32][128];
    const int tid = threadIdx.x;
    const int m_base = blockIdx.x * 128;
    const int nch = (A1 != nullptr) ? 8 : 4;
    float acc[8][8];
#pragma unroll
    for (int i = 0; i < 8; i++)
#pragma unroll
        for (int j = 0; j < 8; j++) acc[i][j] = 0.f;
    const int m0 = (tid >> 4) << 3;
    const int c0 = (tid & 15) << 3;

    for (int ch = 0; ch < nch; ++ch) {
        const int k0 = ch * 32;
        const float* src = (k0 < 128) ? A0 : A1;
        const int kcol = (k0 < 128) ? k0 : (k0 - 128);
        const bool do_elu = (k0 < 128);
        // stage A tile: 128 rows x 32 cols
#pragma unroll
        for (int it = 0; it < 4; ++it) {
            int f = tid + it * 256;         // float4 id, 1024 total
            int r = f >> 3;                 // 8 float4 per row
            int cc = (f & 7) << 2;
            int node = m_base + r;
            float4 v = {0.f, 0.f, 0.f, 0.f};
            if (node < n) v = *(const float4*)(src + (size_t)node * CH + kcol + cc);
            if (do_elu) { v.x = eluf(v.x); v.y = eluf(v.y); v.z = eluf(v.z); v.w = eluf(v.w); }
            As[r][cc]     = v.x;
            As[r][cc + 1] = v.y;
            As[r][cc + 2] = v.z;
            As[r][cc + 3] = v.w;
        }
        // stage W tile: 32 rows x 128 cols
#pragma unroll
        for (int it = 0; it < 4; ++it) {
            int f = tid + it * 256;
            int kr = f >> 5;                // 32 float4 per row
            int wc = (f & 31) << 2;
            float4 v = *(const float4*)(W + (size_t)(k0 + kr) * CH + wc);
            *(float4*)&Ws[kr][wc] = v;
        }
        __syncthreads();
#pragma unroll
        for (int kk = 0; kk < 32; ++kk) {
            float a[8];
#pragma unroll
            for (int i = 0; i < 8; i++) a[i] = As[m0 + i][kk];
            float4 w0 = *(const float4*)&Ws[kk][c0];
            float4 w1 = *(const float4*)&Ws[kk][c0 + 4];
#pragma unroll
            for (int i = 0; i < 8; i++) {
                acc[i][0] += a[i] * w0.x; acc[i][1] += a[i] * w0.y;
                acc[i][2] += a[i] * w0.z; acc[i][3] += a[i] * w0.w;
                acc[i][4] += a[i] * w1.x; acc[i][5] += a[i] * w1.y;
                acc[i][6] += a[i] * w1.z; acc[i][7] += a[i] * w1.w;
            }
        }
        __syncthreads();
    }
    float4 bv0 = *(const float4*)(bias + c0);
    float4 bv1 = *(const float4*)(bias + c0 + 4);
#pragma unroll
    for (int i = 0; i < 8; i++) {
        int node = m_base + m0 + i;
        if (node >= n) continue;
        float4 o0 = {acc[i][0] + bv0.x, acc[i][1] + bv0.y, acc[i][2] + bv0.z, acc[i][3] + bv0.w};
        float4 o1 = {acc[i][4] + bv1.x, acc[i][5] + bv1.y, acc[i][6] + bv1.z, acc[i][7] + bv1.w};
        if (res) {
            float4 r0 = *(const float4*)(res + (size_t)node * CH + c0);
            float4 r1 = *(const float4*)(res + (size_t)node * CH + c0 + 4);
            o0.x += r0.x; o0.y += r0.y; o0.z += r0.z; o0.w += r0.w;
            o1.x += r1.x; o1.y += r1.y; o1.z += r1.z; o1.w += r1.w;
        }
        *(float4*)(out + (size_t)node * CH + c0)     = o0;
        *(float4*)(out + (size_t)node * CH + c0 + 4) = o1;
    }
}

// ---------------- final head: out[n] = elu(x[n]) @ W2 + b2 + inputs[n,0] ----------------
__global__ __launch_bounds__(256) void final_kernel(
    const float* __restrict__ x, const float* __restrict__ W2,
    const float* __restrict__ b2, const float* __restrict__ in,
    float* __restrict__ out, int n)
{
    int wave = (blockIdx.x * blockDim.x + threadIdx.x) >> 6;
    int lane = threadIdx.x & 63;
    if (wave >= n) return;
    float v = eluf(x[(size_t)wave * CH + lane]) * W2[lane]
            + eluf(x[(size_t)wave * CH + 64 + lane]) * W2[64 + lane];
#pragma unroll
    for (int off = 32; off > 0; off >>= 1) v += __shfl_down(v, off, 64);
    if (lane == 0) out[wave] = v + b2[0] + in[(size_t)wave * 3];
}

extern "C" void kernel_launch(void* const* d_in, const int* in_sizes, int n_in,
                              void* d_out, int out_size, void* d_ws, size_t ws_size,
                              hipStream_t stream)
{
    const int*   L_row   = (const int*)d_in[0];
    const int*   L_col   = (const int*)d_in[1];
    const float* L_val   = (const float*)d_in[2];
    const float* mask    = (const float*)d_in[3];
    const float* inputs  = (const float*)d_in[4];
    const float* conv1_W = (const float*)d_in[5];
    const float* conv1_b = (const float*)d_in[6];
    const float* blocks_W = (const float*)d_in[7];
    const float* blocks_b = (const float*)d_in[8];
    const float* conv2_W = (const float*)d_in[9];
    const float* conv2_b = (const float*)d_in[10];
    float* out = (float*)d_out;

    const int N = N_NODES, E = N_EDGES;
    const size_t NF = (size_t)N * CH;
    const int NPAD = 50048;  // N rounded up, keeps 16B alignment

    float* ws = (float*)d_ws;
    float* bufA = ws;
    float* bufB = bufA + NF;
    float* bufC = bufB + NF;
    float* prop = bufC + NF;
    int* cnt     = (int*)(prop + NF);
    int* cursor  = cnt + NPAD;
    int* row_ptr = cursor + NPAD;
    int* col_s   = row_ptr + NPAD;
    float* val_s = (float*)(col_s + E);
    float* acc_base = val_s + E;          // 14 slots x 128 floats
    float* denom    = acc_base + 14 * CH; // 1 float (padded 16)
    float* bias2    = denom + 16;         // 128 floats

    // upfront zeroing + CSR build (same every call)
    zero_int_kernel<<<(2 * NPAD + 255) / 256, 256, 0, stream>>>(cnt, 2 * NPAD);
    zero_float_kernel<<<(14 * CH + 16 + 255) / 256, 256, 0, stream>>>(acc_base, 14 * CH + 16);
    count_kernel<<<(E + 255) / 256, 256, 0, stream>>>(L_row, cnt, E);
    scan_kernel<<<1, 1024, 0, stream>>>(cnt, row_ptr, N);
    fill_kernel<<<(E + 255) / 256, 256, 0, stream>>>(L_row, L_col, L_val, cursor,
                                                     row_ptr, col_s, val_s, E);
    mask_sum_kernel<<<64, 256, 0, stream>>>(mask, denom, N);

    conv1_kernel<<<(N * CH + 255) / 256, 256, 0, stream>>>(inputs, conv1_W, conv1_b, bufA, N);

    float* bufs[3] = {bufA, bufB, bufC};
    int cur = 0;
    const int gemm_grid = (N + 127) / 128;      // 391
    const int wave_grid = (N + 3) / 4;          // 12500 blocks of 4 waves

    for (int i = 0; i < N_LAYERS; ++i) {
        float* t1 = bufs[(cur + 1) % 3];
        float* t2 = bufs[(cur + 2) % 3];
        const float* xin = bufs[cur];
        for (int j = 0; j < 2; ++j) {
            const float* W = blocks_W + (size_t)(i * 2 + j) * 256 * CH;
            const float* b = blocks_b + (size_t)(i * 2 + j) * CH;
            const float* src = (j == 0) ? xin : t1;
            float* dst = (j == 0) ? t1 : t2;
            const float* resp = (j == 1) ? xin : nullptr;
            if (i % 2 == 0) {
                lap_kernel<<<wave_grid, 256, 0, stream>>>(row_ptr, col_s, val_s, src, prop, N);
                gemm_kernel<<<gemm_grid, 256, 0, stream>>>(src, prop, W, b, resp, dst, N);
            } else {
                float* acc = acc_base + (size_t)(((i - 1) / 2) * 2 + j) * CH;
                avg_reduce_kernel<<<256, 256, 0, stream>>>(src, mask, acc, N);
                avg_bias_kernel<<<1, 256, 0, stream>>>(acc, denom, W + 128 * CH, b, bias2);
                gemm_kernel<<<gemm_grid, 256, 0, stream>>>(src, nullptr, W, bias2, resp, dst, N);
            }
        }
        cur = (cur + 2) % 3;
    }
    final_kernel<<<wave_grid, 256, 0, stream>>>(bufs[cur], conv2_W, conv2_b, inputs, out, N);
}

// Round 3
// 2988.664 us; speedup vs baseline: 1.3374x; 1.1216x over previous
//
#include <hip/hip_runtime.h>
#include <hip/hip_bf16.h>

#define N_NODES 50000
#define N_EDGES 600000
#define CH 128
#define N_LAYERS 15

typedef float f32x4 __attribute__((ext_vector_type(4)));
typedef short s16x8 __attribute__((ext_vector_type(8)));

__device__ __forceinline__ float eluf(float v) {
    return v > 0.f ? v : (__expf(v) - 1.f);
}

// float -> bf16 with round-to-nearest-even, as raw ushort
__device__ __forceinline__ unsigned short f2bf(float f) {
    unsigned int u = __float_as_uint(f);
    unsigned int r = (u + 0x7FFFu + ((u >> 16) & 1u)) >> 16;
    return (unsigned short)r;
}
__device__ __forceinline__ float bf2f(unsigned short h) {
    return __uint_as_float(((unsigned int)h) << 16);
}

// ---------------- conv1: [N,3] @ [3,128] + b ----------------
__global__ __launch_bounds__(256) void conv1_kernel(
    const float* __restrict__ in, const float* __restrict__ W1,
    const float* __restrict__ b1, float* __restrict__ x, int n)
{
    int idx = blockIdx.x * blockDim.x + threadIdx.x;
    if (idx >= n * CH) return;
    int node = idx >> 7;
    int c = idx & 127;
    float o = b1[c]
            + in[(size_t)node * 3 + 0] * W1[0 * CH + c]
            + in[(size_t)node * 3 + 1] * W1[1 * CH + c]
            + in[(size_t)node * 3 + 2] * W1[2 * CH + c];
    x[idx] = o;
}

// ---------------- zero helpers ----------------
__global__ __launch_bounds__(256) void zero_int_kernel(int* __restrict__ p, int n) {
    int i = blockIdx.x * blockDim.x + threadIdx.x;
    if (i < n) p[i] = 0;
}
__global__ __launch_bounds__(256) void zero_float_kernel(float* __restrict__ p, int n) {
    int i = blockIdx.x * blockDim.x + threadIdx.x;
    if (i < n) p[i] = 0.f;
}

// ---------------- CSR build ----------------
__global__ __launch_bounds__(256) void count_kernel(
    const int* __restrict__ row, int* __restrict__ cnt, int e)
{
    int i = blockIdx.x * blockDim.x + threadIdx.x;
    if (i < e) atomicAdd(&cnt[row[i]], 1);
}

// parallel scan: (1) per-block reduce, (2) scan of 49 block sums, (3) per-block scan + offset
__global__ __launch_bounds__(1024) void block_reduce_kernel(
    const int* __restrict__ cnt, int* __restrict__ bsum, int n)
{
    __shared__ int sd[1024];
    int tid = threadIdx.x;
    int i = blockIdx.x * 1024 + tid;
    sd[tid] = (i < n) ? cnt[i] : 0;
    __syncthreads();
    for (int off = 512; off > 0; off >>= 1) {
        if (tid < off) sd[tid] += sd[tid + off];
        __syncthreads();
    }
    if (tid == 0) bsum[blockIdx.x] = sd[0];
}

__global__ __launch_bounds__(64) void scan_small_kernel(
    const int* __restrict__ bsum, int* __restrict__ boff, int nb)
{
    int lane = threadIdx.x;
    int orig = (lane < nb) ? bsum[lane] : 0;
    int v = orig;
#pragma unroll
    for (int d = 1; d < 64; d <<= 1) {
        int t = __shfl_up(v, d, 64);
        if (lane >= d) v += t;
    }
    if (lane < nb) boff[lane] = v - orig;  // exclusive
}

__global__ __launch_bounds__(1024) void block_scan_kernel(
    const int* __restrict__ cnt, const int* __restrict__ boff,
    int* __restrict__ row_ptr, int n)
{
    __shared__ int sd[1024];
    int tid = threadIdx.x;
    int i = blockIdx.x * 1024 + tid;
    sd[tid] = (i < n) ? cnt[i] : 0;
    __syncthreads();
    for (int off = 1; off < 1024; off <<= 1) {
        int t = (tid >= off) ? sd[tid - off] : 0;
        __syncthreads();
        sd[tid] += t;
        __syncthreads();
    }
    if (i < n) row_ptr[i + 1] = sd[tid] + boff[blockIdx.x];
    if (i == 0) row_ptr[0] = 0;
}

__global__ __launch_bounds__(256) void fill_kernel(
    const int* __restrict__ row, const int* __restrict__ col,
    const float* __restrict__ val, int* __restrict__ cursor,
    const int* __restrict__ row_ptr, int* __restrict__ col_s,
    float* __restrict__ val_s, int e)
{
    int i = blockIdx.x * blockDim.x + threadIdx.x;
    if (i >= e) return;
    int r = row[i];
    int pos = atomicAdd(&cursor[r], 1);
    int dst = row_ptr[r] + pos;
    col_s[dst] = col[i];
    val_s[dst] = val[i];
}

// ---------------- mask denominator (once per call) ----------------
__global__ __launch_bounds__(256) void mask_sum_kernel(
    const float* __restrict__ mask, float* __restrict__ denom, int n)
{
    __shared__ float sd[256];
    int tid = threadIdx.x;
    float s = 0.f;
    for (int i = blockIdx.x * 256 + tid; i < n; i += gridDim.x * 256) s += mask[i];
    sd[tid] = s;
    __syncthreads();
    for (int off = 128; off > 0; off >>= 1) {
        if (tid < off) sd[tid] += sd[tid + off];
        __syncthreads();
    }
    if (tid == 0) atomicAdd(denom, sd[0]);
}

// ---------------- W pre-split: fp32 [30][256][128] -> 3 bf16 planes transposed [30][3][128][256]
__global__ __launch_bounds__(256) void split_w_kernel(
    const float* __restrict__ W, unsigned short* __restrict__ Wt, int total)
{
    int id = blockIdx.x * 256 + threadIdx.x;
    if (id >= total) return;
    int s = id >> 15;             // /32768
    int rem = id & 32767;
    int k = rem >> 7;
    int nn = rem & 127;
    float a = W[id];
    unsigned short hi = f2bf(a);
    float r = a - bf2f(hi);
    unsigned short mi = f2bf(r);
    float r2 = r - bf2f(mi);
    unsigned short lo = f2bf(r2);
    size_t base = (size_t)s * 3 * 32768 + (size_t)nn * 256 + k;
    Wt[base]             = hi;
    Wt[base + 32768]     = mi;
    Wt[base + 2 * 32768] = lo;
}

// ---------------- Laplacian: prop[n,:] = sum_e val*elu(x[col,:]) ----------------
__global__ __launch_bounds__(256) void lap_kernel(
    const int* __restrict__ rp, const int* __restrict__ cols,
    const float* __restrict__ vals, const float* __restrict__ x,
    float* __restrict__ prop, int n)
{
    int wave = (blockIdx.x * blockDim.x + threadIdx.x) >> 6;
    int lane = threadIdx.x & 63;
    if (wave >= n) return;
    int s = rp[wave], e = rp[wave + 1];
    int c = lane * 2;
    float2 acc = {0.f, 0.f};
    for (int t = s; t < e; ++t) {
        int col = cols[t];
        float v = vals[t];
        float2 h = *(const float2*)(x + (size_t)col * CH + c);
        h.x = eluf(h.x); h.y = eluf(h.y);
        acc.x += v * h.x; acc.y += v * h.y;
    }
    *(float2*)(prop + (size_t)wave * CH + c) = acc;
}

// ---------------- avg layer: atomic accumulate sum of mask*elu(x) into acc[128] ----------------
__global__ __launch_bounds__(256) void avg_reduce_kernel(
    const float* __restrict__ x, const float* __restrict__ mask,
    float* __restrict__ acc, int n)
{
    __shared__ float sd[256];
    int c = threadIdx.x & 127;
    int sub = threadIdx.x >> 7;
    int rowid = blockIdx.x * 2 + sub;
    float a = 0.f;
    for (int node = rowid; node < n; node += gridDim.x * 2) {
        a += mask[node] * eluf(x[(size_t)node * CH + c]);
    }
    sd[threadIdx.x] = a;
    __syncthreads();
    if (threadIdx.x < 128)
        atomicAdd(&acc[threadIdx.x], sd[threadIdx.x] + sd[threadIdx.x + 128]);
}

// bias2[c] = b[c] + sum_k (acc[k]/denom) * Wb[k][c]
__global__ __launch_bounds__(256) void avg_bias_kernel(
    const float* __restrict__ acc, const float* __restrict__ denom,
    const float* __restrict__ Wb, const float* __restrict__ b,
    float* __restrict__ bias2)
{
    __shared__ float avg_s[128];
    __shared__ float partial[256];
    int tid = threadIdx.x;
    if (tid < 128) avg_s[tid] = acc[tid] / denom[0];
    __syncthreads();
    int c = tid & 127;
    int h = tid >> 7;
    float o = 0.f;
#pragma unroll 8
    for (int k = h * 64; k < h * 64 + 64; ++k) o += avg_s[k] * Wb[(size_t)k * CH + c];
    partial[tid] = o;
    __syncthreads();
    if (tid < 128) bias2[tid] = b[tid] + partial[tid] + partial[tid + 128];
}

// ---------------- MFMA GEMM with 3-way bf16 split (fp32-accurate) ----------------
// out[128 rows/block][128 cols] = elu(A0) @ W[0:128] (+ A1 @ W[128:256]) + bias (+ res)
// Wt: 3 planes, transposed [p][n=128][k=256] bf16. nch: K/32 (8 = lap, 4 = avg).
__global__ __launch_bounds__(256) void gemm_mfma_kernel(
    const float* __restrict__ A0, const float* __restrict__ A1,
    const unsigned short* __restrict__ Wt, const float* __restrict__ bias,
    const float* __restrict__ res, float* __restrict__ out, int n, int nch)
{
    // rows padded to 40 shorts (80 B): 16B-aligned ds b128, <=2-way bank alias
    __shared__ unsigned short As[3][128][40];
    __shared__ unsigned short Bs[3][128][40];
    const int tid = threadIdx.x;
    const int m_base = blockIdx.x * 128;
    const int wid = tid >> 6;
    const int lane = tid & 63;
    const int wm = wid & 1, wn = wid >> 1;     // 2x2 waves of 64x64
    const int q = lane >> 4, c16 = lane & 15;

    f32x4 acc[4][4];
#pragma unroll
    for (int i = 0; i < 4; i++)
#pragma unroll
        for (int j = 0; j < 4; j++) acc[i][j] = (f32x4){0.f, 0.f, 0.f, 0.f};

    for (int ch = 0; ch < nch; ++ch) {
        const int k0 = ch * 32;
        const float* src = (k0 < 128) ? A0 : A1;
        const int kcol = k0 & 127;
        const bool do_elu = (k0 < 128);
        // ---- stage A: 128 rows x 32 k fp32 -> split into 3 bf16 planes
#pragma unroll
        for (int it = 0; it < 4; ++it) {
            int f = tid + it * 256;          // 0..1023 float4 ids
            int r = f >> 3;
            int cc = (f & 7) << 2;           // k offset (floats)
            int node = m_base + r;
            float4 v = {0.f, 0.f, 0.f, 0.f};
            if (node < n) v = *(const float4*)(src + (size_t)node * CH + kcol + cc);
            if (do_elu) { v.x = eluf(v.x); v.y = eluf(v.y); v.z = eluf(v.z); v.w = eluf(v.w); }
            float a[4] = {v.x, v.y, v.z, v.w};
            ushort4 h4, m4, l4;
            unsigned short* hp = (unsigned short*)&h4;
            unsigned short* mp = (unsigned short*)&m4;
            unsigned short* lp = (unsigned short*)&l4;
#pragma unroll
            for (int u = 0; u < 4; ++u) {
                unsigned short hi = f2bf(a[u]);
                float r1 = a[u] - bf2f(hi);
                unsigned short mi = f2bf(r1);
                float r2 = r1 - bf2f(mi);
                hp[u] = hi; mp[u] = mi; lp[u] = f2bf(r2);
            }
            *(ushort4*)&As[0][r][cc] = h4;
            *(ushort4*)&As[1][r][cc] = m4;
            *(ushort4*)&As[2][r][cc] = l4;
        }
        // ---- stage W: 3 planes, tile [n=128][k=32] bf16, 16B chunks
#pragma unroll
        for (int it = 0; it < 6; ++it) {
            int f = tid + it * 256;          // 0..1535
            int p = f >> 9;
            int w = f & 511;
            int r = w >> 2;
            int cc = (w & 3) << 3;           // k offset (shorts)
            uint4 v = *(const uint4*)(Wt + (size_t)p * 32768 + (size_t)r * 256 + k0 + cc);
            *(uint4*)&Bs[p][r][cc] = v;
        }
        __syncthreads();
        // ---- frags + 6-term split MFMA
        s16x8 a0[4], a1[4], a2[4], b0[4], b1[4], b2[4];
#pragma unroll
        for (int mt = 0; mt < 4; ++mt) {
            int m = wm * 64 + mt * 16 + c16;
            a0[mt] = *(const s16x8*)&As[0][m][q * 8];
            a1[mt] = *(const s16x8*)&As[1][m][q * 8];
            a2[mt] = *(const s16x8*)&As[2][m][q * 8];
        }
#pragma unroll
        for (int nt = 0; nt < 4; ++nt) {
            int nr = wn * 64 + nt * 16 + c16;
            b0[nt] = *(const s16x8*)&Bs[0][nr][q * 8];
            b1[nt] = *(const s16x8*)&Bs[1][nr][q * 8];
            b2[nt] = *(const s16x8*)&Bs[2][nr][q * 8];
        }
#pragma unroll
        for (int mt = 0; mt < 4; ++mt)
#pragma unroll
            for (int nt = 0; nt < 4; ++nt) {
                f32x4 c = acc[mt][nt];
                c = __builtin_amdgcn_mfma_f32_16x16x32_bf16(a0[mt], b0[nt], c, 0, 0, 0);
                c = __builtin_amdgcn_mfma_f32_16x16x32_bf16(a0[mt], b1[nt], c, 0, 0, 0);
                c = __builtin_amdgcn_mfma_f32_16x16x32_bf16(a1[mt], b0[nt], c, 0, 0, 0);
                c = __builtin_amdgcn_mfma_f32_16x16x32_bf16(a0[mt], b2[nt], c, 0, 0, 0);
                c = __builtin_amdgcn_mfma_f32_16x16x32_bf16(a2[mt], b0[nt], c, 0, 0, 0);
                c = __builtin_amdgcn_mfma_f32_16x16x32_bf16(a1[mt], b1[nt], c, 0, 0, 0);
                acc[mt][nt] = c;
            }
        __syncthreads();
    }
    // ---- epilogue: D[row=q*4+r][col=c16] per 16x16 tile
#pragma unroll
    for (int mt = 0; mt < 4; ++mt) {
#pragma unroll
        for (int nt = 0; nt < 4; ++nt) {
            int col = wn * 64 + nt * 16 + c16;
            float bv = bias[col];
            int row0 = m_base + wm * 64 + mt * 16 + q * 4;
#pragma unroll
            for (int r = 0; r < 4; ++r) {
                int row = row0 + r;
                if (row < n) {
                    float o = acc[mt][nt][r] + bv;
                    if (res) o += res[(size_t)row * CH + col];
                    out[(size_t)row * CH + col] = o;
                }
            }
        }
    }
}

// ---------------- final head: out[n] = elu(x[n]) @ W2 + b2 + inputs[n,0] ----------------
__global__ __launch_bounds__(256) void final_kernel(
    const float* __restrict__ x, const float* __restrict__ W2,
    const float* __restrict__ b2, const float* __restrict__ in,
    float* __restrict__ out, int n)
{
    int wave = (blockIdx.x * blockDim.x + threadIdx.x) >> 6;
    int lane = threadIdx.x & 63;
    if (wave >= n) return;
    float v = eluf(x[(size_t)wave * CH + lane]) * W2[lane]
            + eluf(x[(size_t)wave * CH + 64 + lane]) * W2[64 + lane];
#pragma unroll
    for (int off = 32; off > 0; off >>= 1) v += __shfl_down(v, off, 64);
    if (lane == 0) out[wave] = v + b2[0] + in[(size_t)wave * 3];
}

extern "C" void kernel_launch(void* const* d_in, const int* in_sizes, int n_in,
                              void* d_out, int out_size, void* d_ws, size_t ws_size,
                              hipStream_t stream)
{
    const int*   L_row   = (const int*)d_in[0];
    const int*   L_col   = (const int*)d_in[1];
    const float* L_val   = (const float*)d_in[2];
    const float* mask    = (const float*)d_in[3];
    const float* inputs  = (const float*)d_in[4];
    const float* conv1_W = (const float*)d_in[5];
    const float* conv1_b = (const float*)d_in[6];
    const float* blocks_W = (const float*)d_in[7];
    const float* blocks_b = (const float*)d_in[8];
    const float* conv2_W = (const float*)d_in[9];
    const float* conv2_b = (const float*)d_in[10];
    float* out = (float*)d_out;

    const int N = N_NODES, E = N_EDGES;
    const size_t NF = (size_t)N * CH;
    const int NPAD = 50048;
    const int NB = (N + 1023) / 1024;   // 49 scan blocks

    float* ws = (float*)d_ws;
    float* bufA = ws;
    float* bufB = bufA + NF;
    float* bufC = bufB + NF;
    float* prop = bufC + NF;
    int* cnt     = (int*)(prop + NF);
    int* cursor  = cnt + NPAD;
    int* row_ptr = cursor + NPAD;
    int* bsum    = row_ptr + NPAD;
    int* boff    = bsum + 64;
    int* col_s   = boff + 64;
    float* val_s = (float*)(col_s + E);
    float* acc_base = val_s + E;            // 14 slots x 128
    float* denom    = acc_base + 14 * CH;
    float* bias2    = denom + 16;
    unsigned short* wt = (unsigned short*)(bias2 + 128 + 32);  // 30*3*32768 shorts = 5.9MB

    // upfront: zero, CSR build, mask sum, W split
    zero_int_kernel<<<(2 * NPAD + 255) / 256, 256, 0, stream>>>(cnt, 2 * NPAD);
    zero_float_kernel<<<(14 * CH + 16 + 255) / 256, 256, 0, stream>>>(acc_base, 14 * CH + 16);
    count_kernel<<<(E + 255) / 256, 256, 0, stream>>>(L_row, cnt, E);
    block_reduce_kernel<<<NB, 1024, 0, stream>>>(cnt, bsum, N);
    scan_small_kernel<<<1, 64, 0, stream>>>(bsum, boff, NB);
    block_scan_kernel<<<NB, 1024, 0, stream>>>(cnt, boff, row_ptr, N);
    fill_kernel<<<(E + 255) / 256, 256, 0, stream>>>(L_row, L_col, L_val, cursor,
                                                     row_ptr, col_s, val_s, E);
    mask_sum_kernel<<<64, 256, 0, stream>>>(mask, denom, N);
    split_w_kernel<<<(30 * 32768 + 255) / 256, 256, 0, stream>>>(blocks_W, wt, 30 * 32768);

    conv1_kernel<<<(N * CH + 255) / 256, 256, 0, stream>>>(inputs, conv1_W, conv1_b, bufA, N);

    float* bufs[3] = {bufA, bufB, bufC};
    int cur = 0;
    const int gemm_grid = (N + 127) / 128;      // 391
    const int wave_grid = (N + 3) / 4;

    for (int i = 0; i < N_LAYERS; ++i) {
        float* t1 = bufs[(cur + 1) % 3];
        float* t2 = bufs[(cur + 2) % 3];
        const float* xin = bufs[cur];
        for (int j = 0; j < 2; ++j) {
            int s = i * 2 + j;
            const unsigned short* Wt_s = wt + (size_t)s * 3 * 32768;
            const float* b = blocks_b + (size_t)s * CH;
            const float* src = (j == 0) ? xin : t1;
            float* dst = (j == 0) ? t1 : t2;
            const float* resp = (j == 1) ? xin : nullptr;
            if (i % 2 == 0) {
                lap_kernel<<<wave_grid, 256, 0, stream>>>(row_ptr, col_s, val_s, src, prop, N);
                gemm_mfma_kernel<<<gemm_grid, 256, 0, stream>>>(src, prop, Wt_s, b, resp, dst, N, 8);
            } else {
                float* acc = acc_base + (size_t)(((i - 1) / 2) * 2 + j) * CH;
                avg_reduce_kernel<<<256, 256, 0, stream>>>(src, mask, acc, N);
                avg_bias_kernel<<<1, 256, 0, stream>>>(acc, denom,
                    blocks_W + (size_t)s * 256 * CH + 128 * CH, b, bias2);
                gemm_mfma_kernel<<<gemm_grid, 256, 0, stream>>>(src, nullptr, Wt_s, bias2, resp, dst, N, 4);
            }
        }
        cur = (cur + 2) % 3;
    }
    final_kernel<<<wave_grid, 256, 0, stream>>>(bufs[cur], conv2_W, conv2_b, inputs, out, N);
}